// Round 1
// baseline (1751.975 us; speedup 1.0000x reference)
//
#include <hip/hip_runtime.h>
#include <stdint.h>

typedef unsigned short u16;
typedef __bf16 bf16x8 __attribute__((ext_vector_type(8)));
typedef float f32x4 __attribute__((ext_vector_type(4)));

#define AS1 __attribute__((address_space(1)))
#define AS3 __attribute__((address_space(3)))

// async global->LDS, 16B per lane. HW writes wave-uniform base + lane*16.
static __device__ __forceinline__ void gload16(const void* g, void* l) {
  __builtin_amdgcn_global_load_lds((const AS1 unsigned int*)g,
                                   (AS3 unsigned int*)l, 16, 0, 0);
}

static __device__ __forceinline__ u16 f2bf(float f) {
  unsigned u = __float_as_uint(f);
  u += 0x7fffu + ((u >> 16) & 1u);   // RNE; inputs are finite/tame
  return (u16)(u >> 16);
}

union BF8 { uint4 u; bf16x8 b; };
static __device__ __forceinline__ bf16x8 ldg_bf8(const u16* p) {
  BF8 t; t.u = *(const uint4*)p; return t.b;
}

// ---------------------------------------------------------------------------
// Transpose + fp32->bf16 convert: in (L,R,C) f32 -> out (L,C,R) bf16.
// grid = (C/32, R/32, L), block = 256
// ---------------------------------------------------------------------------
__global__ __launch_bounds__(256) void transpose_bf16(
    const float* __restrict__ in, u16* __restrict__ out, int R, int C)
{
  __shared__ float t[32][33];
  const size_t base = (size_t)blockIdx.z * R * C;
  const float* ip = in + base;
  u16* op = out + base;
  const int c0 = blockIdx.x * 32, r0 = blockIdx.y * 32;
  const int tx = threadIdx.x & 31, ty = threadIdx.x >> 5;  // 32 x 8
#pragma unroll
  for (int i = 0; i < 4; i++)
    t[ty + i * 8][tx] = ip[(size_t)(r0 + ty + i * 8) * C + (c0 + tx)];
  __syncthreads();
#pragma unroll
  for (int i = 0; i < 4; i++)
    op[(size_t)(c0 + ty + i * 8) * R + (r0 + tx)] = f2bf(t[tx][ty + i * 8]);
}

// ---------------------------------------------------------------------------
// Embedding gather: h[s][:] = tok_emb[tok[s]][:]. grid=2048, block=256
// ---------------------------------------------------------------------------
__global__ __launch_bounds__(256) void embed_k(
    const int* __restrict__ tok, const float* __restrict__ emb, float* __restrict__ h)
{
  const int s = blockIdx.x;
  const int t = tok[s];
  ((float4*)(h + (size_t)s * 1024))[threadIdx.x] =
      ((const float4*)(emb + (size_t)t * 1024))[threadIdx.x];
}

// ---------------------------------------------------------------------------
// RMSNorm row -> bf16. grid=2048 (one block/row), block=256 (4 elems/thread)
// ---------------------------------------------------------------------------
__global__ __launch_bounds__(256) void rmsnorm_bf16(
    const float* __restrict__ x, const float* __restrict__ w, u16* __restrict__ y)
{
  const int s = blockIdx.x, tid = threadIdx.x;
  const float4 v = ((const float4*)(x + (size_t)s * 1024))[tid];
  float ss = v.x * v.x + v.y * v.y + v.z * v.z + v.w * v.w;
#pragma unroll
  for (int off = 32; off; off >>= 1) ss += __shfl_xor(ss, off);
  __shared__ float red[4];
  if ((tid & 63) == 0) red[tid >> 6] = ss;
  __syncthreads();
  const float tot = red[0] + red[1] + red[2] + red[3];
  const float sc = rsqrtf(tot * (1.0f / 1024.0f) + 1e-6f);
  const float4 wv = ((const float4*)w)[tid];
  ushort4 o;
  o.x = f2bf(v.x * sc * wv.x);
  o.y = f2bf(v.y * sc * wv.y);
  o.z = f2bf(v.z * sc * wv.z);
  o.w = f2bf(v.w * sc * wv.w);
  ((ushort4*)(y + (size_t)s * 1024))[tid] = o;
}

// ---------------------------------------------------------------------------
// GEMM: C(MxN) [f32] = A(MxK)[bf16, lda=K] @ Bt(NxK)[bf16, ldb=K]^T  (+C if doAdd)
// m97 structure: 128x128 tile, BK=32, 4 waves (2x2), 4x4 16x16x32 frags/wave,
// global_load_lds width=16 staging. grid=(N/128, M/128, z); z picks B/C set.
// ---------------------------------------------------------------------------
__global__ __launch_bounds__(256) void gemm_bt(
    int M, int N, int K,
    const u16* __restrict__ A,
    const u16* __restrict__ Bz0, const u16* __restrict__ Bz1, const u16* __restrict__ Bz2,
    float* __restrict__ Cz0, float* __restrict__ Cz1, float* __restrict__ Cz2,
    int doAdd)
{
  const u16* B = (blockIdx.z == 0) ? Bz0 : (blockIdx.z == 1) ? Bz1 : Bz2;
  float*    C = (blockIdx.z == 0) ? Cz0 : (blockIdx.z == 1) ? Cz1 : Cz2;
  __shared__ u16 As[128 * 32];
  __shared__ u16 Bs[128 * 32];
  const int tid = threadIdx.x;
  const int wave = tid >> 6, lane = tid & 63;
  const int lm = lane & 15, quad = lane >> 4;
  const int wm = wave >> 1, wn = wave & 1;
  const int m0 = blockIdx.y * 128, n0 = blockIdx.x * 128;

  // staging: chunk c covers A row (c>>2), k-part (c&3)*8, 8 bf16 = 16B
  const int c0 = tid, c1 = tid + 256;
  const u16* ga0 = A + (size_t)(m0 + (c0 >> 2)) * K + (c0 & 3) * 8;
  const u16* ga1 = A + (size_t)(m0 + (c1 >> 2)) * K + (c1 & 3) * 8;
  const u16* gb0 = B + (size_t)(n0 + (c0 >> 2)) * K + (c0 & 3) * 8;
  const u16* gb1 = B + (size_t)(n0 + (c1 >> 2)) * K + (c1 & 3) * 8;
  u16* la0 = &As[c0 * 8];
  u16* la1 = &As[c1 * 8];
  u16* lb0 = &Bs[c0 * 8];
  u16* lb1 = &Bs[c1 * 8];

  f32x4 acc[4][4];
#pragma unroll
  for (int i = 0; i < 4; i++)
#pragma unroll
    for (int j = 0; j < 4; j++) acc[i][j] = (f32x4){0.f, 0.f, 0.f, 0.f};

  const u16* arp = &As[(wm * 64 + lm) * 32 + quad * 8];
  const u16* brp = &Bs[(wn * 64 + lm) * 32 + quad * 8];

  for (int k0 = 0; k0 < K; k0 += 32) {
    __syncthreads();          // previous iter's LDS reads done
    gload16(ga0 + k0, la0);
    gload16(ga1 + k0, la1);
    gload16(gb0 + k0, lb0);
    gload16(gb1 + k0, lb1);
    __syncthreads();          // drains vmcnt(0): staging complete
    bf16x8 af[4], bfv[4];
#pragma unroll
    for (int mi = 0; mi < 4; mi++) af[mi] = *(const bf16x8*)(arp + mi * 16 * 32);
#pragma unroll
    for (int ni = 0; ni < 4; ni++) bfv[ni] = *(const bf16x8*)(brp + ni * 16 * 32);
#pragma unroll
    for (int mi = 0; mi < 4; mi++)
#pragma unroll
      for (int ni = 0; ni < 4; ni++)
        acc[mi][ni] = __builtin_amdgcn_mfma_f32_16x16x32_bf16(af[mi], bfv[ni], acc[mi][ni], 0, 0, 0);
  }

  // C/D layout: col = lane&15, row = quad*4 + r
#pragma unroll
  for (int mi = 0; mi < 4; mi++) {
    const int row = m0 + wm * 64 + mi * 16 + quad * 4;
#pragma unroll
    for (int ni = 0; ni < 4; ni++) {
      const int col = n0 + wn * 64 + ni * 16 + lm;
      float* cp = C + (size_t)row * N + col;
      if (doAdd) {
#pragma unroll
        for (int r = 0; r < 4; r++) cp[(size_t)r * N] += acc[mi][ni][r];
      } else {
#pragma unroll
        for (int r = 0; r < 4; r++) cp[(size_t)r * N] = acc[mi][ni][r];
      }
    }
  }
}

// ---------------------------------------------------------------------------
// RoPE on q,k (fp32 in) -> bf16 out. 1 thread per (s, head, pair).
// grid = 4096, block = 256  (2048*16*32 = 1M pairs)
// ---------------------------------------------------------------------------
__global__ __launch_bounds__(256) void rope_qk(
    const float* __restrict__ qf, const float* __restrict__ kf,
    u16* __restrict__ qb, u16* __restrict__ kb)
{
  const int idx = blockIdx.x * 256 + threadIdx.x;
  const int s = idx >> 9;          // 512 pairs per position
  const int p = idx & 511;
  const int h = p >> 5, i = p & 31;
  const size_t o = (size_t)s * 1024 + h * 64 + 2 * i;
  const float freq = __expf((float)i * (-9.210340371976184f / 32.0f)); // theta^{-2i/64}
  const float ang = (float)s * freq;
  float sn, cs;
  sincosf(ang, &sn, &cs);
  const float2 q = *(const float2*)(qf + o);
  const float2 k = *(const float2*)(kf + o);
  ushort2 qo, ko;
  qo.x = f2bf(q.x * cs - q.y * sn); qo.y = f2bf(q.x * sn + q.y * cs);
  ko.x = f2bf(k.x * cs - k.y * sn); ko.y = f2bf(k.x * sn + k.y * cs);
  *(ushort2*)(qb + o) = qo;
  *(ushort2*)(kb + o) = ko;
}

// ---------------------------------------------------------------------------
// Flash attention, causal, bf16 MFMA. grid=(32, 16 heads), block=256 (4 waves).
// Wave w: 16-query tile q0 = bx*64 + w*16; loops 32-key chunks with online
// softmax. Q/K frags straight from global (k-contiguous); V pre-transposed
// vT[h*64+d][s]. P goes C/D-layout -> LDS(f32) -> A-layout (per-wave, no
// block barriers: waves have different causal trip counts).
// ---------------------------------------------------------------------------
__global__ __launch_bounds__(256) void attn_fa(
    const u16* __restrict__ Q, const u16* __restrict__ Kb,
    const u16* __restrict__ Vt, u16* __restrict__ O)
{
  const int head = blockIdx.y;
  const int wave = threadIdx.x >> 6, lane = threadIdx.x & 63;
  const int lm = lane & 15, quad = lane >> 4;
  const int q0 = blockIdx.x * 64 + wave * 16;
  __shared__ __align__(16) float Pb[4][16][36];   // stride 36: 16B-aligned rows
  float (*P)[36] = Pb[wave];
  const float scale = 0.125f;   // 1/sqrt(64)

  const u16* qp = Q + (size_t)(q0 + lm) * 1024 + head * 64 + quad * 8;
  const bf16x8 aq0 = ldg_bf8(qp);        // A[m=lm][k=quad*8+j], d 0..31
  const bf16x8 aq1 = ldg_bf8(qp + 32);   // d 32..63

  f32x4 o[4];
#pragma unroll
  for (int i = 0; i < 4; i++) o[i] = (f32x4){0.f, 0.f, 0.f, 0.f};
  float mrun[4] = {-1e30f, -1e30f, -1e30f, -1e30f};
  float lrun[4] = {0.f, 0.f, 0.f, 0.f};

  for (int kc = 0; kc < q0 + 16; kc += 32) {
    const u16* kp = Kb + (size_t)(kc + lm) * 1024 + head * 64 + quad * 8;
    const bf16x8 b00 = ldg_bf8(kp);                         // keys kc..kc+15, d lo
    const bf16x8 b01 = ldg_bf8(kp + 32);                    //                d hi
    const bf16x8 b10 = ldg_bf8(kp + (size_t)16 * 1024);     // keys kc+16..kc+31
    const bf16x8 b11 = ldg_bf8(kp + (size_t)16 * 1024 + 32);
    const f32x4 z = (f32x4){0.f, 0.f, 0.f, 0.f};
    f32x4 S0 = __builtin_amdgcn_mfma_f32_16x16x32_bf16(aq0, b00, z, 0, 0, 0);
    S0 = __builtin_amdgcn_mfma_f32_16x16x32_bf16(aq1, b01, S0, 0, 0, 0);
    f32x4 S1 = __builtin_amdgcn_mfma_f32_16x16x32_bf16(aq0, b10, z, 0, 0, 0);
    S1 = __builtin_amdgcn_mfma_f32_16x16x32_bf16(aq1, b11, S1, 0, 0, 0);

    float p0[4], p1[4], alpha[4], mx[4], rs[4];
#pragma unroll
    for (int r = 0; r < 4; r++) {
      const int i = q0 + quad * 4 + r;           // query row (C/D layout)
      float s0 = S0[r] * scale; if (kc + lm > i) s0 = -1e30f;        // causal
      float s1 = S1[r] * scale; if (kc + 16 + lm > i) s1 = -1e30f;
      p0[r] = s0; p1[r] = s1;
      mx[r] = fmaxf(s0, s1);
    }
#pragma unroll
    for (int off = 1; off < 16; off <<= 1)
#pragma unroll
      for (int r = 0; r < 4; r++) mx[r] = fmaxf(mx[r], __shfl_xor(mx[r], off));
#pragma unroll
    for (int r = 0; r < 4; r++) {
      const float mnew = fmaxf(mrun[r], mx[r]);
      alpha[r] = __expf(mrun[r] - mnew);
      mrun[r] = mnew;
      p0[r] = __expf(p0[r] - mnew);
      p1[r] = __expf(p1[r] - mnew);
      rs[r] = p0[r] + p1[r];
    }
#pragma unroll
    for (int off = 1; off < 16; off <<= 1)
#pragma unroll
      for (int r = 0; r < 4; r++) rs[r] += __shfl_xor(rs[r], off);
#pragma unroll
    for (int r = 0; r < 4; r++) {
      lrun[r] = lrun[r] * alpha[r] + rs[r];
      P[quad * 4 + r][lm] = p0[r];
      P[quad * 4 + r][16 + lm] = p1[r];
      o[0][r] *= alpha[r]; o[1][r] *= alpha[r];
      o[2][r] *= alpha[r]; o[3][r] *= alpha[r];
    }
    // P: C/D layout -> A layout (same wave; lgkmcnt ordering handled by compiler)
    const float* pr = &P[lm][quad * 8];
    const float4 pa = *(const float4*)pr;
    const float4 pc = *(const float4*)(pr + 4);
    BF8 t;
    u16* ts = (u16*)&t;
    ts[0] = f2bf(pa.x); ts[1] = f2bf(pa.y); ts[2] = f2bf(pa.z); ts[3] = f2bf(pa.w);
    ts[4] = f2bf(pc.x); ts[5] = f2bf(pc.y); ts[6] = f2bf(pc.z); ts[7] = f2bf(pc.w);
    const bf16x8 ap = t.b;
    const u16* vp = Vt + (size_t)(head * 64 + lm) * 2048 + kc + quad * 8;
#pragma unroll
    for (int nd = 0; nd < 4; nd++) {
      const bf16x8 bv = ldg_bf8(vp + (size_t)nd * 16 * 2048);  // B[k=key][n=d]
      o[nd] = __builtin_amdgcn_mfma_f32_16x16x32_bf16(ap, bv, o[nd], 0, 0, 0);
    }
  }

#pragma unroll
  for (int r = 0; r < 4; r++) {
    const float inv = 1.0f / lrun[r];
    const int row = q0 + quad * 4 + r;
    u16* op = O + (size_t)row * 1024 + head * 64 + lm;
#pragma unroll
    for (int nd = 0; nd < 4; nd++) op[nd * 16] = f2bf(o[nd][r] * inv);
  }
}

// ---------------------------------------------------------------------------
// u = bf16( silu(g1) * g3 ). grid=5632, block=256, float4 per thread.
// ---------------------------------------------------------------------------
__global__ __launch_bounds__(256) void silu_mul(
    const float* __restrict__ g1, const float* __restrict__ g3, u16* __restrict__ u)
{
  const int idx = blockIdx.x * 256 + threadIdx.x;
  const float4 a = ((const float4*)g1)[idx];
  const float4 b = ((const float4*)g3)[idx];
  ushort4 o;
  o.x = f2bf(a.x / (1.f + __expf(-a.x)) * b.x);
  o.y = f2bf(a.y / (1.f + __expf(-a.y)) * b.y);
  o.z = f2bf(a.z / (1.f + __expf(-a.z)) * b.z);
  o.w = f2bf(a.w / (1.f + __expf(-a.w)) * b.w);
  ((ushort4*)u)[idx] = o;
}

// ---------------------------------------------------------------------------
// Final RMSNorm of last row (fp32 out). 1 block, 256 threads.
// ---------------------------------------------------------------------------
__global__ __launch_bounds__(256) void final_norm(
    const float* __restrict__ h, const float* __restrict__ w, float* __restrict__ xn)
{
  const int tid = threadIdx.x;
  const float4 v = ((const float4*)(h + (size_t)2047 * 1024))[tid];
  float ss = v.x * v.x + v.y * v.y + v.z * v.z + v.w * v.w;
#pragma unroll
  for (int off = 32; off; off >>= 1) ss += __shfl_xor(ss, off);
  __shared__ float red[4];
  if ((tid & 63) == 0) red[tid >> 6] = ss;
  __syncthreads();
  const float tot = red[0] + red[1] + red[2] + red[3];
  const float sc = rsqrtf(tot * (1.0f / 1024.0f) + 1e-6f);
  const float4 wv = ((const float4*)w)[tid];
  float4 o;
  o.x = v.x * sc * wv.x; o.y = v.y * sc * wv.y;
  o.z = v.z * sc * wv.z; o.w = v.w * sc * wv.w;
  ((float4*)xn)[tid] = o;
}

// ---------------------------------------------------------------------------
// logits[v] += sum over 256-d slice of xn[d]*Wout[d][v]. grid=(125,4), fp32.
// ---------------------------------------------------------------------------
__global__ __launch_bounds__(256) void logits_k(
    const float* __restrict__ xn, const float* __restrict__ Wout, float* __restrict__ out)
{
  const int v = blockIdx.x * 256 + threadIdx.x;
  const int dp = blockIdx.y;
  const float* xp = xn + dp * 256;
  const float* wp = Wout + (size_t)dp * 256 * 32000 + v;
  float acc = 0.f;
#pragma unroll 8
  for (int d = 0; d < 256; d++) acc = fmaf(xp[d], wp[(size_t)d * 32000], acc);
  atomicAdd(out + v, acc);
}

// ---------------------------------------------------------------------------
extern "C" void kernel_launch(void* const* d_in, const int* in_sizes, int n_in,
                              void* d_out, int out_size, void* d_ws, size_t ws_size,
                              hipStream_t stream) {
  const int S = 2048, D = 1024, HFF = 2816, L = 4;
  const int* tokens = (const int*)d_in[0];
  // d_in[1] = num_heads (16, hardcoded)
  const float* tok_emb = (const float*)d_in[2];
  const float* Wq = (const float*)d_in[3];
  const float* Wk = (const float*)d_in[4];
  const float* Wv = (const float*)d_in[5];
  const float* Wo = (const float*)d_in[6];
  const float* W1 = (const float*)d_in[7];
  const float* W2 = (const float*)d_in[8];   // note dict order: W2 before W3
  const float* W3 = (const float*)d_in[9];
  const float* anw  = (const float*)d_in[10];
  const float* fnw  = (const float*)d_in[11];
  const float* finw = (const float*)d_in[12];
  const float* Wout = (const float*)d_in[13];

  char* w = (char*)d_ws;
  size_t off = 0;
  auto take = [&](size_t b) { size_t o = off; off += (b + 255) & ~(size_t)255; return o; };
  const size_t szDD = (size_t)L * D * D * 2;       // 8 MB bf16
  const size_t szDH = (size_t)L * D * HFF * 2;     // 23 MB bf16
  u16* WqT = (u16*)(w + take(szDD));
  u16* WkT = (u16*)(w + take(szDD));
  u16* WvT = (u16*)(w + take(szDD));
  u16* WoT = (u16*)(w + take(szDD));
  u16* W1T = (u16*)(w + take(szDH));
  u16* W3T = (u16*)(w + take(szDH));
  u16* W2T = (u16*)(w + take(szDH));
  float* h  = (float*)(w + take((size_t)S * D * 4));
  u16*   xb = (u16*)(w + take((size_t)S * D * 2));
  // union region: {qf,kf,vf,qbb,kbb,vTb,ob} (attention) vs {g1,g3,u} (FFN)
  const size_t region = take((size_t)2 * S * HFF * 4 + (size_t)S * HFF * 2);
  float* qf = (float*)(w + region);
  float* kf = qf + (size_t)S * D;
  float* vf = kf + (size_t)S * D;
  u16* qbb = (u16*)(vf + (size_t)S * D);
  u16* kbb = qbb + (size_t)S * D;
  u16* vTb = kbb + (size_t)S * D;
  u16* ob  = vTb + (size_t)S * D;
  float* g1 = (float*)(w + region);
  float* g3 = g1 + (size_t)S * HFF;
  u16*  ub  = (u16*)(g3 + (size_t)S * HFF);
  float* xn = (float*)(w + take(4096));
  (void)ws_size; (void)in_sizes; (void)n_in; (void)out_size;  // need ~165 MB ws

  const dim3 blk(256);
  // one-time (per call) weight transpose+convert to bf16 B^T
  transpose_bf16<<<dim3(32, 32, 4), blk, 0, stream>>>(Wq, WqT, D, D);
  transpose_bf16<<<dim3(32, 32, 4), blk, 0, stream>>>(Wk, WkT, D, D);
  transpose_bf16<<<dim3(32, 32, 4), blk, 0, stream>>>(Wv, WvT, D, D);
  transpose_bf16<<<dim3(32, 32, 4), blk, 0, stream>>>(Wo, WoT, D, D);
  transpose_bf16<<<dim3(88, 32, 4), blk, 0, stream>>>(W1, W1T, D, HFF);
  transpose_bf16<<<dim3(88, 32, 4), blk, 0, stream>>>(W3, W3T, D, HFF);
  transpose_bf16<<<dim3(32, 88, 4), blk, 0, stream>>>(W2, W2T, HFF, D);
  embed_k<<<2048, blk, 0, stream>>>(tokens, tok_emb, h);

  for (int l = 0; l < L; l++) {
    const size_t oDD = (size_t)l * D * D;
    const size_t oDH = (size_t)l * D * HFF;
    rmsnorm_bf16<<<2048, blk, 0, stream>>>(h, anw + l * D, xb);
    gemm_bt<<<dim3(8, 16, 3), blk, 0, stream>>>(S, D, D, xb,
        WqT + oDD, WkT + oDD, WvT + oDD, qf, kf, vf, 0);
    rope_qk<<<4096, blk, 0, stream>>>(qf, kf, qbb, kbb);
    transpose_bf16<<<dim3(32, 64, 1), blk, 0, stream>>>(vf, vTb, S, D);
    attn_fa<<<dim3(32, 16), blk, 0, stream>>>(qbb, kbb, vTb, ob);
    gemm_bt<<<dim3(8, 16, 1), blk, 0, stream>>>(S, D, D, ob,
        WoT + oDD, WoT + oDD, WoT + oDD, h, h, h, 1);
    rmsnorm_bf16<<<2048, blk, 0, stream>>>(h, fnw + l * D, xb);
    gemm_bt<<<dim3(22, 16, 2), blk, 0, stream>>>(S, HFF, D, xb,
        W1T + oDH, W3T + oDH, W3T + oDH, g1, g3, g3, 0);
    silu_mul<<<5632, blk, 0, stream>>>(g1, g3, ub);
    gemm_bt<<<dim3(8, 16, 1), blk, 0, stream>>>(S, D, HFF, ub,
        W2T + oDH, W2T + oDH, W2T + oDH, h, h, h, 1);
  }
  final_norm<<<1, blk, 0, stream>>>(h, finw, xn);
  hipMemsetAsync(d_out, 0, 32000 * sizeof(float), stream);
  logits_k<<<dim3(125, 4), blk, 0, stream>>>(xn, Wout, (float*)d_out);
}

// Round 2
// 1591.367 us; speedup vs baseline: 1.1009x; 1.1009x over previous
//
#include <hip/hip_runtime.h>
#include <stdint.h>

typedef unsigned short u16;
typedef __bf16 bf16x8 __attribute__((ext_vector_type(8)));
typedef float f32x4 __attribute__((ext_vector_type(4)));

#define AS1 __attribute__((address_space(1)))
#define AS3 __attribute__((address_space(3)))

// async global->LDS, 16B per lane. HW writes wave-uniform base + lane*16.
static __device__ __forceinline__ void gload16(const void* g, void* l) {
  __builtin_amdgcn_global_load_lds((const AS1 unsigned int*)g,
                                   (AS3 unsigned int*)l, 16, 0, 0);
}

static __device__ __forceinline__ u16 f2bf(float f) {
  unsigned u = __float_as_uint(f);
  u += 0x7fffu + ((u >> 16) & 1u);   // RNE; inputs are finite/tame
  return (u16)(u >> 16);
}

union BF8 { uint4 u; bf16x8 b; };
static __device__ __forceinline__ bf16x8 ldg_bf8(const u16* p) {
  BF8 t; t.u = *(const uint4*)p; return t.b;
}

// ---------------------------------------------------------------------------
// Transpose + fp32->bf16 convert: in (L,R,C) f32 -> out (L,C,R) bf16.
// grid = (C/32, R/32, L), block = 256
// ---------------------------------------------------------------------------
__global__ __launch_bounds__(256) void transpose_bf16(
    const float* __restrict__ in, u16* __restrict__ out, int R, int C)
{
  __shared__ float t[32][33];
  const size_t base = (size_t)blockIdx.z * R * C;
  const float* ip = in + base;
  u16* op = out + base;
  const int c0 = blockIdx.x * 32, r0 = blockIdx.y * 32;
  const int tx = threadIdx.x & 31, ty = threadIdx.x >> 5;  // 32 x 8
#pragma unroll
  for (int i = 0; i < 4; i++)
    t[ty + i * 8][tx] = ip[(size_t)(r0 + ty + i * 8) * C + (c0 + tx)];
  __syncthreads();
#pragma unroll
  for (int i = 0; i < 4; i++)
    op[(size_t)(c0 + ty + i * 8) * R + (r0 + tx)] = f2bf(t[tx][ty + i * 8]);
}

// ---------------------------------------------------------------------------
// Embedding gather: h[s][:] = tok_emb[tok[s]][:]. grid=2048, block=256
// ---------------------------------------------------------------------------
__global__ __launch_bounds__(256) void embed_k(
    const int* __restrict__ tok, const float* __restrict__ emb, float* __restrict__ h)
{
  const int s = blockIdx.x;
  const int t = tok[s];
  ((float4*)(h + (size_t)s * 1024))[threadIdx.x] =
      ((const float4*)(emb + (size_t)t * 1024))[threadIdx.x];
}

// ---------------------------------------------------------------------------
// RMSNorm row -> bf16. grid=2048 (one block/row), block=256 (4 elems/thread)
// ---------------------------------------------------------------------------
__global__ __launch_bounds__(256) void rmsnorm_bf16(
    const float* __restrict__ x, const float* __restrict__ w, u16* __restrict__ y)
{
  const int s = blockIdx.x, tid = threadIdx.x;
  const float4 v = ((const float4*)(x + (size_t)s * 1024))[tid];
  float ss = v.x * v.x + v.y * v.y + v.z * v.z + v.w * v.w;
#pragma unroll
  for (int off = 32; off; off >>= 1) ss += __shfl_xor(ss, off);
  __shared__ float red[4];
  if ((tid & 63) == 0) red[tid >> 6] = ss;
  __syncthreads();
  const float tot = red[0] + red[1] + red[2] + red[3];
  const float sc = rsqrtf(tot * (1.0f / 1024.0f) + 1e-6f);
  const float4 wv = ((const float4*)w)[tid];
  ushort4 o;
  o.x = f2bf(v.x * sc * wv.x);
  o.y = f2bf(v.y * sc * wv.y);
  o.z = f2bf(v.z * sc * wv.z);
  o.w = f2bf(v.w * sc * wv.w);
  ((ushort4*)(y + (size_t)s * 1024))[tid] = o;
}

// ---------------------------------------------------------------------------
// GEMM: C(MxN) [f32] = A(MxK)[bf16, lda=K] @ Bt(NxK)[bf16, ldb=K]^T  (+C if doAdd)
// m97 structure: 128x128 tile, BK=32, 4 waves (2x2), 4x4 16x16x32 frags/wave,
// global_load_lds width=16 staging. grid=(N/128, M/128, z); z picks B/C set.
// ---------------------------------------------------------------------------
__global__ __launch_bounds__(256) void gemm_bt(
    int M, int N, int K,
    const u16* __restrict__ A,
    const u16* __restrict__ Bz0, const u16* __restrict__ Bz1, const u16* __restrict__ Bz2,
    float* __restrict__ Cz0, float* __restrict__ Cz1, float* __restrict__ Cz2,
    int doAdd)
{
  const u16* B = (blockIdx.z == 0) ? Bz0 : (blockIdx.z == 1) ? Bz1 : Bz2;
  float*    C = (blockIdx.z == 0) ? Cz0 : (blockIdx.z == 1) ? Cz1 : Cz2;
  __shared__ u16 As[128 * 32];
  __shared__ u16 Bs[128 * 32];
  const int tid = threadIdx.x;
  const int wave = tid >> 6, lane = tid & 63;
  const int lm = lane & 15, quad = lane >> 4;
  const int wm = wave >> 1, wn = wave & 1;
  const int m0 = blockIdx.y * 128, n0 = blockIdx.x * 128;

  const int c0 = tid, c1 = tid + 256;
  const u16* ga0 = A + (size_t)(m0 + (c0 >> 2)) * K + (c0 & 3) * 8;
  const u16* ga1 = A + (size_t)(m0 + (c1 >> 2)) * K + (c1 & 3) * 8;
  const u16* gb0 = B + (size_t)(n0 + (c0 >> 2)) * K + (c0 & 3) * 8;
  const u16* gb1 = B + (size_t)(n0 + (c1 >> 2)) * K + (c1 & 3) * 8;
  u16* la0 = &As[c0 * 8];
  u16* la1 = &As[c1 * 8];
  u16* lb0 = &Bs[c0 * 8];
  u16* lb1 = &Bs[c1 * 8];

  f32x4 acc[4][4];
#pragma unroll
  for (int i = 0; i < 4; i++)
#pragma unroll
    for (int j = 0; j < 4; j++) acc[i][j] = (f32x4){0.f, 0.f, 0.f, 0.f};

  const u16* arp = &As[(wm * 64 + lm) * 32 + quad * 8];
  const u16* brp = &Bs[(wn * 64 + lm) * 32 + quad * 8];

  for (int k0 = 0; k0 < K; k0 += 32) {
    __syncthreads();
    gload16(ga0 + k0, la0);
    gload16(ga1 + k0, la1);
    gload16(gb0 + k0, lb0);
    gload16(gb1 + k0, lb1);
    __syncthreads();
    bf16x8 af[4], bfv[4];
#pragma unroll
    for (int mi = 0; mi < 4; mi++) af[mi] = *(const bf16x8*)(arp + mi * 16 * 32);
#pragma unroll
    for (int ni = 0; ni < 4; ni++) bfv[ni] = *(const bf16x8*)(brp + ni * 16 * 32);
#pragma unroll
    for (int mi = 0; mi < 4; mi++)
#pragma unroll
      for (int ni = 0; ni < 4; ni++)
        acc[mi][ni] = __builtin_amdgcn_mfma_f32_16x16x32_bf16(af[mi], bfv[ni], acc[mi][ni], 0, 0, 0);
  }

#pragma unroll
  for (int mi = 0; mi < 4; mi++) {
    const int row = m0 + wm * 64 + mi * 16 + quad * 4;
#pragma unroll
    for (int ni = 0; ni < 4; ni++) {
      const int col = n0 + wn * 64 + ni * 16 + lm;
      float* cp = C + (size_t)row * N + col;
      if (doAdd) {
#pragma unroll
        for (int r = 0; r < 4; r++) cp[(size_t)r * N] += acc[mi][ni][r];
      } else {
#pragma unroll
        for (int r = 0; r < 4; r++) cp[(size_t)r * N] = acc[mi][ni][r];
      }
    }
  }
}

// ---------------------------------------------------------------------------
// GEMM 128x64 tile variant, always C += A@B^T. grid=(N/64, M/128), block=256.
// 4 waves stacked in M (32 rows each); per-wave 2x4 frags. For the N=1024
// GEMMs (O-proj, FFN2): grid = 16x16 = 256 blocks = exactly 1/CU (the 128x128
// tile gave only 128 blocks -> half the chip idle).
// ---------------------------------------------------------------------------
__global__ __launch_bounds__(256) void gemm_bt64(
    int M, int N, int K, const u16* __restrict__ A, const u16* __restrict__ B,
    float* __restrict__ C)
{
  __shared__ u16 As[128 * 32];
  __shared__ u16 Bs[64 * 32];
  const int tid = threadIdx.x;
  const int wave = tid >> 6, lane = tid & 63;
  const int lm = lane & 15, quad = lane >> 4;
  const int m0 = blockIdx.y * 128, n0 = blockIdx.x * 64;

  const int c0 = tid, c1 = tid + 256;
  const u16* ga0 = A + (size_t)(m0 + (c0 >> 2)) * K + (c0 & 3) * 8;
  const u16* ga1 = A + (size_t)(m0 + (c1 >> 2)) * K + (c1 & 3) * 8;
  const u16* gb0 = B + (size_t)(n0 + (c0 >> 2)) * K + (c0 & 3) * 8;
  u16* la0 = &As[c0 * 8];
  u16* la1 = &As[c1 * 8];
  u16* lb0 = &Bs[c0 * 8];

  f32x4 acc[2][4];
#pragma unroll
  for (int i = 0; i < 2; i++)
#pragma unroll
    for (int j = 0; j < 4; j++) acc[i][j] = (f32x4){0.f, 0.f, 0.f, 0.f};

  const u16* arp = &As[(wave * 32 + lm) * 32 + quad * 8];
  const u16* brp = &Bs[lm * 32 + quad * 8];

  for (int k0 = 0; k0 < K; k0 += 32) {
    __syncthreads();
    gload16(ga0 + k0, la0);
    gload16(ga1 + k0, la1);
    gload16(gb0 + k0, lb0);
    __syncthreads();
    bf16x8 af[2], bfv[4];
#pragma unroll
    for (int mi = 0; mi < 2; mi++) af[mi] = *(const bf16x8*)(arp + mi * 16 * 32);
#pragma unroll
    for (int ni = 0; ni < 4; ni++) bfv[ni] = *(const bf16x8*)(brp + ni * 16 * 32);
#pragma unroll
    for (int mi = 0; mi < 2; mi++)
#pragma unroll
      for (int ni = 0; ni < 4; ni++)
        acc[mi][ni] = __builtin_amdgcn_mfma_f32_16x16x32_bf16(af[mi], bfv[ni], acc[mi][ni], 0, 0, 0);
  }

#pragma unroll
  for (int mi = 0; mi < 2; mi++) {
    const int row = m0 + wave * 32 + mi * 16 + quad * 4;
#pragma unroll
    for (int ni = 0; ni < 4; ni++) {
      const int col = n0 + ni * 16 + lm;
      float* cp = C + (size_t)row * N + col;
#pragma unroll
      for (int r = 0; r < 4; r++) cp[(size_t)r * N] += acc[mi][ni][r];
    }
  }
}

// ---------------------------------------------------------------------------
// RoPE on q,k (fp32 in) -> bf16 out. grid = 4096, block = 256
// ---------------------------------------------------------------------------
__global__ __launch_bounds__(256) void rope_qk(
    const float* __restrict__ qf, const float* __restrict__ kf,
    u16* __restrict__ qb, u16* __restrict__ kb)
{
  const int idx = blockIdx.x * 256 + threadIdx.x;
  const int s = idx >> 9;          // 512 pairs per position
  const int p = idx & 511;
  const int h = p >> 5, i = p & 31;
  const size_t o = (size_t)s * 1024 + h * 64 + 2 * i;
  const float freq = __expf((float)i * (-9.210340371976184f / 32.0f)); // theta^{-2i/64}
  const float ang = (float)s * freq;
  float sn, cs;
  sincosf(ang, &sn, &cs);
  const float2 q = *(const float2*)(qf + o);
  const float2 k = *(const float2*)(kf + o);
  ushort2 qo, ko;
  qo.x = f2bf(q.x * cs - q.y * sn); qo.y = f2bf(q.x * sn + q.y * cs);
  ko.x = f2bf(k.x * cs - k.y * sn); ko.y = f2bf(k.x * sn + k.y * cs);
  *(ushort2*)(qb + o) = qo;
  *(ushort2*)(kb + o) = ko;
}

// ---------------------------------------------------------------------------
// Flash attention v2, causal, bf16 MFMA. grid=(32, 16 heads), block=256.
// Wave w handles 16 queries; 64-key chunks; K register-double-buffered
// (prefetch next chunk's K before computing current), V issued at chunk top
// so QK+softmax latency hides it. Longest blocks dispatch first (qblk=31-bx)
// to kill the causal tail. No block barriers (per-wave LDS region for the P
// C/D->A layout round-trip).
// ---------------------------------------------------------------------------
struct KFr { bf16x8 b[8]; };

__global__ __launch_bounds__(256) void attn_fa(
    const u16* __restrict__ Q, const u16* __restrict__ Kb,
    const u16* __restrict__ Vt, u16* __restrict__ O)
{
  const int head = blockIdx.y;
  const int wave = threadIdx.x >> 6, lane = threadIdx.x & 63;
  const int lm = lane & 15, quad = lane >> 4;
  const int qblk = 31 - blockIdx.x;          // longest first
  const int q0 = qblk * 64 + wave * 16;
  const int nc = qblk + 1;                   // 64-key chunks (uniform per block)
  __shared__ __align__(16) float Pb[4][16][72];   // stride 72: 2-way banks, 16B rows
  float (*P)[72] = Pb[wave];
  const float scale = 0.125f;   // 1/sqrt(64)

  const u16* qp = Q + (size_t)(q0 + lm) * 1024 + head * 64 + quad * 8;
  const bf16x8 aq0 = ldg_bf8(qp);        // A[m=lm][k=quad*8+j], d 0..31
  const bf16x8 aq1 = ldg_bf8(qp + 32);   // d 32..63

  f32x4 o[4];
#pragma unroll
  for (int i = 0; i < 4; i++) o[i] = (f32x4){0.f, 0.f, 0.f, 0.f};
  float mrun[4] = {-1e30f, -1e30f, -1e30f, -1e30f};
  float lrun[4] = {0.f, 0.f, 0.f, 0.f};

  auto loadK = [&](KFr& kr, int kc) {
    const u16* kp = Kb + (size_t)(kc + lm) * 1024 + head * 64 + quad * 8;
#pragma unroll
    for (int j = 0; j < 4; j++) {
      kr.b[j * 2 + 0] = ldg_bf8(kp + (size_t)j * 16 * 1024);        // keys kc+16j+lm, d lo
      kr.b[j * 2 + 1] = ldg_bf8(kp + (size_t)j * 16 * 1024 + 32);   //                 d hi
    }
  };

  auto compute = [&](const KFr& kr, int kc) {
    // V loads issued first; consumed only after softmax (~300 cyc later)
    bf16x8 vv[8];
    const u16* vp = Vt + (size_t)(head * 64 + lm) * 2048 + kc + quad * 8;
#pragma unroll
    for (int nd = 0; nd < 4; nd++) {
      vv[nd * 2 + 0] = ldg_bf8(vp + (size_t)nd * 16 * 2048);        // keys kc..+31
      vv[nd * 2 + 1] = ldg_bf8(vp + (size_t)nd * 16 * 2048 + 32);   // keys kc+32..+63
    }
    const f32x4 z = (f32x4){0.f, 0.f, 0.f, 0.f};
    f32x4 S[4];
#pragma unroll
    for (int j = 0; j < 4; j++) {
      S[j] = __builtin_amdgcn_mfma_f32_16x16x32_bf16(aq0, kr.b[j * 2 + 0], z, 0, 0, 0);
      S[j] = __builtin_amdgcn_mfma_f32_16x16x32_bf16(aq1, kr.b[j * 2 + 1], S[j], 0, 0, 0);
    }
    float p[4][4], alpha[4], mx[4], rs[4];
#pragma unroll
    for (int r = 0; r < 4; r++) {
      const int row = q0 + quad * 4 + r;
      mx[r] = -1e30f;
#pragma unroll
      for (int j = 0; j < 4; j++) {
        float s = S[j][r] * scale;
        if (kc + j * 16 + lm > row) s = -1e30f;      // causal
        p[j][r] = s;
        mx[r] = fmaxf(mx[r], s);
      }
    }
#pragma unroll
    for (int off = 1; off < 16; off <<= 1)
#pragma unroll
      for (int r = 0; r < 4; r++) mx[r] = fmaxf(mx[r], __shfl_xor(mx[r], off));
#pragma unroll
    for (int r = 0; r < 4; r++) {
      const float mnew = fmaxf(mrun[r], mx[r]);
      alpha[r] = __expf(mrun[r] - mnew);
      mrun[r] = mnew;
      rs[r] = 0.f;
#pragma unroll
      for (int j = 0; j < 4; j++) {
        p[j][r] = __expf(p[j][r] - mnew);
        rs[r] += p[j][r];
      }
    }
#pragma unroll
    for (int off = 1; off < 16; off <<= 1)
#pragma unroll
      for (int r = 0; r < 4; r++) rs[r] += __shfl_xor(rs[r], off);
#pragma unroll
    for (int r = 0; r < 4; r++) {
      lrun[r] = lrun[r] * alpha[r] + rs[r];
#pragma unroll
      for (int j = 0; j < 4; j++) P[quad * 4 + r][j * 16 + lm] = p[j][r];
      o[0][r] *= alpha[r]; o[1][r] *= alpha[r];
      o[2][r] *= alpha[r]; o[3][r] *= alpha[r];
    }
    // P: C/D layout -> two A-layout frags (keys 0..31, 32..63); same-wave LDS
    const float* pr0 = &P[lm][quad * 8];
    const float4 pa = *(const float4*)pr0;
    const float4 pb2 = *(const float4*)(pr0 + 4);
    const float4 pc = *(const float4*)(pr0 + 32);
    const float4 pd = *(const float4*)(pr0 + 36);
    BF8 t0, t1;
    u16* s0 = (u16*)&t0; u16* s1 = (u16*)&t1;
    s0[0] = f2bf(pa.x); s0[1] = f2bf(pa.y); s0[2] = f2bf(pa.z); s0[3] = f2bf(pa.w);
    s0[4] = f2bf(pb2.x); s0[5] = f2bf(pb2.y); s0[6] = f2bf(pb2.z); s0[7] = f2bf(pb2.w);
    s1[0] = f2bf(pc.x); s1[1] = f2bf(pc.y); s1[2] = f2bf(pc.z); s1[3] = f2bf(pc.w);
    s1[4] = f2bf(pd.x); s1[5] = f2bf(pd.y); s1[6] = f2bf(pd.z); s1[7] = f2bf(pd.w);
#pragma unroll
    for (int nd = 0; nd < 4; nd++) {
      o[nd] = __builtin_amdgcn_mfma_f32_16x16x32_bf16(t0.b, vv[nd * 2 + 0], o[nd], 0, 0, 0);
      o[nd] = __builtin_amdgcn_mfma_f32_16x16x32_bf16(t1.b, vv[nd * 2 + 1], o[nd], 0, 0, 0);
    }
  };

  KFr kA, kB;
  loadK(kA, 0);
  int c = 0;
  while (true) {
    if (c + 1 < nc) loadK(kB, (c + 1) * 64);
    compute(kA, c * 64);
    if (++c == nc) break;
    if (c + 1 < nc) loadK(kA, (c + 1) * 64);
    compute(kB, c * 64);
    if (++c == nc) break;
  }

#pragma unroll
  for (int r = 0; r < 4; r++) {
    const float inv = 1.0f / lrun[r];
    const int row = q0 + quad * 4 + r;
    u16* op = O + (size_t)row * 1024 + head * 64 + lm;
#pragma unroll
    for (int nd = 0; nd < 4; nd++) op[nd * 16] = f2bf(o[nd][r] * inv);
  }
}

// ---------------------------------------------------------------------------
// u = bf16( silu(g1) * g3 ). grid=5632, block=256, float4 per thread.
// ---------------------------------------------------------------------------
__global__ __launch_bounds__(256) void silu_mul(
    const float* __restrict__ g1, const float* __restrict__ g3, u16* __restrict__ u)
{
  const int idx = blockIdx.x * 256 + threadIdx.x;
  const float4 a = ((const float4*)g1)[idx];
  const float4 b = ((const float4*)g3)[idx];
  ushort4 o;
  o.x = f2bf(a.x / (1.f + __expf(-a.x)) * b.x);
  o.y = f2bf(a.y / (1.f + __expf(-a.y)) * b.y);
  o.z = f2bf(a.z / (1.f + __expf(-a.z)) * b.z);
  o.w = f2bf(a.w / (1.f + __expf(-a.w)) * b.w);
  ((ushort4*)u)[idx] = o;
}

// ---------------------------------------------------------------------------
// Final RMSNorm of last row (fp32 out). 1 block, 256 threads.
// ---------------------------------------------------------------------------
__global__ __launch_bounds__(256) void final_norm(
    const float* __restrict__ h, const float* __restrict__ w, float* __restrict__ xn)
{
  const int tid = threadIdx.x;
  const float4 v = ((const float4*)(h + (size_t)2047 * 1024))[tid];
  float ss = v.x * v.x + v.y * v.y + v.z * v.z + v.w * v.w;
#pragma unroll
  for (int off = 32; off; off >>= 1) ss += __shfl_xor(ss, off);
  __shared__ float red[4];
  if ((tid & 63) == 0) red[tid >> 6] = ss;
  __syncthreads();
  const float tot = red[0] + red[1] + red[2] + red[3];
  const float sc = rsqrtf(tot * (1.0f / 1024.0f) + 1e-6f);
  const float4 wv = ((const float4*)w)[tid];
  float4 o;
  o.x = v.x * sc * wv.x; o.y = v.y * sc * wv.y;
  o.z = v.z * sc * wv.z; o.w = v.w * sc * wv.w;
  ((float4*)xn)[tid] = o;
}

// ---------------------------------------------------------------------------
// logits[v] += sum over 256-d slice of xn[d]*Wout[d][v]. grid=(125,4), fp32.
// ---------------------------------------------------------------------------
__global__ __launch_bounds__(256) void logits_k(
    const float* __restrict__ xn, const float* __restrict__ Wout, float* __restrict__ out)
{
  const int v = blockIdx.x * 256 + threadIdx.x;
  const int dp = blockIdx.y;
  const float* xp = xn + dp * 256;
  const float* wp = Wout + (size_t)dp * 256 * 32000 + v;
  float acc = 0.f;
#pragma unroll 8
  for (int d = 0; d < 256; d++) acc = fmaf(xp[d], wp[(size_t)d * 32000], acc);
  atomicAdd(out + v, acc);
}

// ---------------------------------------------------------------------------
extern "C" void kernel_launch(void* const* d_in, const int* in_sizes, int n_in,
                              void* d_out, int out_size, void* d_ws, size_t ws_size,
                              hipStream_t stream) {
  const int S = 2048, D = 1024, HFF = 2816, L = 4;
  const int* tokens = (const int*)d_in[0];
  const float* tok_emb = (const float*)d_in[2];
  const float* Wq = (const float*)d_in[3];
  const float* Wk = (const float*)d_in[4];
  const float* Wv = (const float*)d_in[5];
  const float* Wo = (const float*)d_in[6];
  const float* W1 = (const float*)d_in[7];
  const float* W2 = (const float*)d_in[8];   // dict order: W2 before W3
  const float* W3 = (const float*)d_in[9];
  const float* anw  = (const float*)d_in[10];
  const float* fnw  = (const float*)d_in[11];
  const float* finw = (const float*)d_in[12];
  const float* Wout = (const float*)d_in[13];

  char* w = (char*)d_ws;
  size_t off = 0;
  auto take = [&](size_t b) { size_t o = off; off += (b + 255) & ~(size_t)255; return o; };
  const size_t szDD = (size_t)L * D * D * 2;       // 8 MB bf16
  const size_t szDH = (size_t)L * D * HFF * 2;     // 23 MB bf16
  u16* WqT = (u16*)(w + take(szDD));
  u16* WkT = (u16*)(w + take(szDD));
  u16* WvT = (u16*)(w + take(szDD));
  u16* WoT = (u16*)(w + take(szDD));
  u16* W1T = (u16*)(w + take(szDH));
  u16* W3T = (u16*)(w + take(szDH));
  u16* W2T = (u16*)(w + take(szDH));
  float* h  = (float*)(w + take((size_t)S * D * 4));
  u16*   xb = (u16*)(w + take((size_t)S * D * 2));
  const size_t region = take((size_t)2 * S * HFF * 4 + (size_t)S * HFF * 2);
  float* qf = (float*)(w + region);
  float* kf = qf + (size_t)S * D;
  float* vf = kf + (size_t)S * D;
  u16* qbb = (u16*)(vf + (size_t)S * D);
  u16* kbb = qbb + (size_t)S * D;
  u16* vTb = kbb + (size_t)S * D;
  u16* ob  = vTb + (size_t)S * D;
  float* g1 = (float*)(w + region);
  float* g3 = g1 + (size_t)S * HFF;
  u16*  ub  = (u16*)(g3 + (size_t)S * HFF);
  float* xn = (float*)(w + take(4096));
  (void)ws_size; (void)in_sizes; (void)n_in; (void)out_size;

  const dim3 blk(256);
  transpose_bf16<<<dim3(32, 32, 4), blk, 0, stream>>>(Wq, WqT, D, D);
  transpose_bf16<<<dim3(32, 32, 4), blk, 0, stream>>>(Wk, WkT, D, D);
  transpose_bf16<<<dim3(32, 32, 4), blk, 0, stream>>>(Wv, WvT, D, D);
  transpose_bf16<<<dim3(32, 32, 4), blk, 0, stream>>>(Wo, WoT, D, D);
  transpose_bf16<<<dim3(88, 32, 4), blk, 0, stream>>>(W1, W1T, D, HFF);
  transpose_bf16<<<dim3(88, 32, 4), blk, 0, stream>>>(W3, W3T, D, HFF);
  transpose_bf16<<<dim3(32, 88, 4), blk, 0, stream>>>(W2, W2T, HFF, D);
  embed_k<<<2048, blk, 0, stream>>>(tokens, tok_emb, h);

  for (int l = 0; l < L; l++) {
    const size_t oDD = (size_t)l * D * D;
    const size_t oDH = (size_t)l * D * HFF;
    rmsnorm_bf16<<<2048, blk, 0, stream>>>(h, anw + l * D, xb);
    gemm_bt<<<dim3(8, 16, 3), blk, 0, stream>>>(S, D, D, xb,
        WqT + oDD, WkT + oDD, WvT + oDD, qf, kf, vf, 0);
    rope_qk<<<4096, blk, 0, stream>>>(qf, kf, qbb, kbb);
    transpose_bf16<<<dim3(32, 64, 1), blk, 0, stream>>>(vf, vTb, S, D);
    attn_fa<<<dim3(32, 16), blk, 0, stream>>>(qbb, kbb, vTb, ob);
    gemm_bt64<<<dim3(16, 16), blk, 0, stream>>>(S, D, D, ob, WoT + oDD, h);
    rmsnorm_bf16<<<2048, blk, 0, stream>>>(h, fnw + l * D, xb);
    gemm_bt<<<dim3(22, 16, 2), blk, 0, stream>>>(S, HFF, D, xb,
        W1T + oDH, W3T + oDH, W3T + oDH, g1, g3, g3, 0);
    silu_mul<<<5632, blk, 0, stream>>>(g1, g3, ub);
    gemm_bt64<<<dim3(16, 16), blk, 0, stream>>>(S, D, HFF, ub, W2T + oDH, h);
  }
  final_norm<<<1, blk, 0, stream>>>(h, finw, xn);
  hipMemsetAsync(d_out, 0, 32000 * sizeof(float), stream);
  logits_k<<<dim3(125, 4), blk, 0, stream>>>(xn, Wout, (float*)d_out);
}